// Round 7
// baseline (430.227 us; speedup 1.0000x reference)
//
#include <hip/hip_runtime.h>
#include <hip/hip_cooperative_groups.h>
#include <math.h>

namespace cg = cooperative_groups;

#define N_ROWS   65536
#define K_EMB    1024
#define D_EMB    256

typedef __attribute__((ext_vector_type(8)))  short short8;
typedef __attribute__((ext_vector_type(4)))  short short4v;
typedef __attribute__((ext_vector_type(16))) float floatx16;

__device__ inline unsigned short f2bf(float f) {
    unsigned u = __float_as_uint(f);
    unsigned r = u + 0x7fffu + ((u >> 16) & 1u);
    return (unsigned short)(r >> 16);
}
__device__ inline float bf2f(unsigned short s) {
    return __uint_as_float(((unsigned)s) << 16);
}

// ---------------- prep: 0.5*||e||^2 + negated bf16 hi/lo codebook ----------------
// Pack layout (proven): off = tile*8192 + kt*512 + lane*8 + j  (shorts)
//   tile=code>>5, kt=dim>>4, half=(dim&15)>>3, lane=(code&31)+32*half, j=dim&7.
// A wave's fragment load is 64 lanes x 16B CONTIGUOUS (1 KB).
// Also zeros counts/loss_buckets (no separate memset dispatch).
__global__ __launch_bounds__(64)
void prep_e(const float* __restrict__ ew, float* __restrict__ half_esq,
            short* __restrict__ pack_hi, short* __restrict__ pack_lo,
            int* __restrict__ counts, double* __restrict__ loss_buckets)
{
    const int k = blockIdx.x;
    const int t = threadIdx.x;  // 64 threads, 4 consecutive dims each

    if (t == 0) {
        counts[k] = 0;
        if (k < 256) loss_buckets[k] = 0.0;
    }

    float4 v = *(const float4*)(ew + (size_t)k * D_EMB + t * 4);
    float s = v.x * v.x + v.y * v.y + v.z * v.z + v.w * v.w;
#pragma unroll
    for (int off = 32; off > 0; off >>= 1) s += __shfl_down(s, off);
    if (t == 0) half_esq[k] = 0.5f * s;

    const int d0   = t * 4;
    const int tile = k >> 5;
    const int kt   = d0 >> 4;
    const int half = (d0 & 15) >> 3;
    const int lane = (k & 31) + 32 * half;
    const int j0   = d0 & 7;          // 0 or 4
    const int off  = tile * 8192 + kt * 512 + lane * 8 + j0;

    float f[4] = {-v.x, -v.y, -v.z, -v.w};
    short4v h, l;
#pragma unroll
    for (int j = 0; j < 4; ++j) {
        unsigned short hh = f2bf(f[j]);
        h[j] = (short)hh;
        l[j] = (short)f2bf(f[j] - bf2f(hh));
    }
    *(short4v*)(pack_hi + off) = h;
    *(short4v*)(pack_lo + off) = l;
}

// ---------------- Phase A (fused): MFMA argmin + quantize + loss ----------------
// PROVEN round-2 configuration (142-157 us machine-dependent): 256 threads,
// 32 rows in LDS, 4 waves x 4 code-passes of 2 tiles, depth-1 register
// prefetch, unroll 4, (256,2). CLOSED levers (measured regressions):
//   - 4-tile/4-acc ILP (r1, 234 us) - depth-2 prefetch (r3, 205 us)
//   - 512thr/8-wave TLP: reg cap 64 < acc footprint -> spill (r5, 705 us)
//   - per-row histogram atomic in epilogue (r4, +18 us)
__global__ __launch_bounds__(256, 2)
void argmin_mfma(const float* __restrict__ x,
                 const short* __restrict__ pack_hi,
                 const short* __restrict__ pack_lo,
                 const float* __restrict__ half_esq,
                 const float* __restrict__ ew,
                 int* __restrict__ indices,
                 float* __restrict__ out_q,
                 double* __restrict__ loss_buckets)
{
    __shared__ short xs_hi[32 * 256];
    __shared__ short xs_lo[32 * 256];
    __shared__ float cmv[128];
    __shared__ int   cmi[128];
    __shared__ int   widx[32];

    const int t  = threadIdx.x;
    const int r0 = blockIdx.x * 32;

    // ---- stage x: fp32 -> bf16 hi/lo, swizzled so frag reads are 4-way optimal ----
#pragma unroll
    for (int i = 0; i < 4; ++i) {
        int q   = i * 256 + t;   // [0,1024)
        int row = q >> 5;        // [0,32)
        int g8  = q & 31;        // 8-float group within row
        const float* gp = x + (size_t)(r0 + row) * D_EMB + g8 * 8;
        float4 a = *(const float4*)gp;
        float4 b = *(const float4*)(gp + 4);
        float f[8] = {a.x, a.y, a.z, a.w, b.x, b.y, b.z, b.w};
        short8 h8, l8;
#pragma unroll
        for (int j = 0; j < 8; ++j) {
            unsigned short hh = f2bf(f[j]);
            h8[j] = (short)hh;
            l8[j] = (short)f2bf(f[j] - bf2f(hh));
        }
        int off = row * 256 + ((g8 ^ (row & 7)) << 3);
        *(short8*)(xs_hi + off) = h8;
        *(short8*)(xs_lo + off) = l8;
    }
    __syncthreads();

    const int w    = t >> 6;     // wave id -> code quarter
    const int lane = t & 63;
    const int l31  = lane & 31;
    const int half = lane >> 5;
    const int key  = l31 & 7;    // swizzle key (row == l31)
    const short* bbase_h = xs_hi + l31 * 256;
    const short* bbase_l = xs_lo + l31 * 256;

    float mv = 3.4e38f;
    int   mi = 0;

    for (int cp = 0; cp < 4; ++cp) {
        const int c0 = w * 256 + cp * 64;
        const int c1 = c0 + 32;
        const int tile0 = c0 >> 5;   // tile1 = tile0+1

        floatx16 acc0, acc1;
#pragma unroll
        for (int rq = 0; rq < 4; ++rq) {
            float4 e0 = *(const float4*)(half_esq + c0 + rq * 8 + half * 4);
            float4 e1 = *(const float4*)(half_esq + c1 + rq * 8 + half * 4);
            acc0[rq * 4 + 0] = e0.x; acc0[rq * 4 + 1] = e0.y;
            acc0[rq * 4 + 2] = e0.z; acc0[rq * 4 + 3] = e0.w;
            acc1[rq * 4 + 0] = e1.x; acc1[rq * 4 + 1] = e1.y;
            acc1[rq * 4 + 2] = e1.z; acc1[rq * 4 + 3] = e1.w;
        }

        // fragment-packed bases: wave reads CONTIGUOUS 1 KB per load
        const short* p0h = pack_hi + tile0 * 8192 + lane * 8;
        const short* p0l = pack_lo + tile0 * 8192 + lane * 8;
        const short* p1h = p0h + 8192;
        const short* p1l = p0l + 8192;

        // depth-1 register prefetch ((256,2): no reg cap => no spills)
        short8 a0h = *(const short8*)(p0h);
        short8 a0l = *(const short8*)(p0l);
        short8 a1h = *(const short8*)(p1h);
        short8 a1l = *(const short8*)(p1l);

#pragma unroll 4
        for (int kt = 0; kt < 16; ++kt) {
            short8 n0h, n0l, n1h, n1l;
            if (kt < 15) {
                n0h = *(const short8*)(p0h + (kt + 1) * 512);
                n0l = *(const short8*)(p0l + (kt + 1) * 512);
                n1h = *(const short8*)(p1h + (kt + 1) * 512);
                n1l = *(const short8*)(p1l + (kt + 1) * 512);
            }
            int coff = (((2 * kt + half) ^ key) << 3);
            short8 bh = *(const short8*)(bbase_h + coff);
            short8 bl = *(const short8*)(bbase_l + coff);
            acc0 = __builtin_amdgcn_mfma_f32_32x32x16_bf16(a0h, bh, acc0, 0, 0, 0);
            acc1 = __builtin_amdgcn_mfma_f32_32x32x16_bf16(a1h, bh, acc1, 0, 0, 0);
            acc0 = __builtin_amdgcn_mfma_f32_32x32x16_bf16(a0h, bl, acc0, 0, 0, 0);
            acc1 = __builtin_amdgcn_mfma_f32_32x32x16_bf16(a1h, bl, acc1, 0, 0, 0);
            acc0 = __builtin_amdgcn_mfma_f32_32x32x16_bf16(a0l, bh, acc0, 0, 0, 0);
            acc1 = __builtin_amdgcn_mfma_f32_32x32x16_bf16(a1l, bh, acc1, 0, 0, 0);
            a0h = n0h; a0l = n0l; a1h = n1h; a1l = n1l;
        }

        // fold: C row = code-in-tile = (r&3) + 8*(r>>2) + 4*half; col = x-row = l31
#pragma unroll
        for (int r = 0; r < 16; ++r) {
            int code0 = c0 + (r & 3) + ((r >> 2) << 3) + half * 4;
            float v0 = acc0[r];
            if (v0 < mv || (v0 == mv && code0 < mi)) { mv = v0; mi = code0; }
            int code1 = code0 + 32;
            float v1 = acc1[r];
            if (v1 < mv || (v1 == mv && code1 < mi)) { mv = v1; mi = code1; }
        }
    }

    // combine the two 32-lane halves (disjoint code subsets, same x-row)
    {
        float ov = __shfl_xor(mv, 32);
        int   oi = __shfl_xor(mi, 32);
        if (ov < mv || (ov == mv && oi < mi)) { mv = ov; mi = oi; }
    }

    // cross-wave (code-quarter) combine via dedicated LDS scratch (xs intact)
    if (half == 0) {
        int slot = w * 32 + l31;
        cmv[slot] = mv;
        cmi[slot] = mi;
    }
    __syncthreads();
    if (t < 32) {
        float bv = cmv[t];
        int   bi = cmi[t];
#pragma unroll
        for (int ww = 1; ww < 4; ++ww) {
            float v = cmv[ww * 32 + t];
            int   i = cmi[ww * 32 + t];
            if (v < bv || (v == bv && i < bi)) { bv = v; bi = i; }
        }
        indices[r0 + t] = bi;
        widx[t] = bi;
    }
    __syncthreads();

    // ---- fused epilogue: quantize + commitment-loss partial ----
    const int g8e  = lane >> 1;            // dim group of this lane's 4 dims
    const int j0e  = (lane & 1) * 4;       // offset within the 8-group
    float lsum = 0.0f;
#pragma unroll
    for (int rr = 0; rr < 8; ++rr) {
        const int row = w * 8 + rr;            // wave handles 8 rows
        const int idx = widx[row];             // wave-uniform
        const int off = row * 256 + (((g8e) ^ (row & 7)) << 3) + j0e;
        short4v h4 = *(const short4v*)(xs_hi + off);
        short4v l4 = *(const short4v*)(xs_lo + off);
        float xr[4];
#pragma unroll
        for (int j = 0; j < 4; ++j)
            xr[j] = bf2f((unsigned short)h4[j]) + bf2f((unsigned short)l4[j]);
        const float4 ev = *(const float4*)(ew + (size_t)idx * D_EMB + lane * 4);
        float4 q;
        q.x = xr[0] + (ev.x - xr[0]);
        q.y = xr[1] + (ev.y - xr[1]);
        q.z = xr[2] + (ev.z - xr[2]);
        q.w = xr[3] + (ev.w - xr[3]);
        *(float4*)(out_q + (size_t)(r0 + row) * D_EMB + lane * 4) = q;
        float dx = ev.x - xr[0], dy = ev.y - xr[1];
        float dz = ev.z - xr[2], dwv = ev.w - xr[3];
        lsum += dx * dx + dy * dy + dz * dz + dwv * dwv;
    }
#pragma unroll
    for (int off = 32; off > 0; off >>= 1) lsum += __shfl_down(lsum, off);
    if (lane == 0) atomicAdd(&loss_buckets[blockIdx.x & 255], (double)lsum);
}

// ---------------- tail (cooperative): hist -> scan/scalars -> scatter -> gather ----
// ONE kernel replaces 4 dispatches (histogram, finalize, scatter, gather) to
// eliminate inter-dispatch bubbles. 512 blocks x 256 threads: needs only
// 2 blocks/CU co-resident (capacity ~8 at 16 KB LDS, <=128 VGPR).
//   A: blocks 0-15 LDS-histogram their 4096-row slice -> global counts
//   B: block 0: prefix-scan -> offsets, cluster-size scalars, perp, loss
//   C: all blocks scatter 128 rows each (counting sort placement)
//   D: block b handles codes 2b,2b+1: gather x rows + EMA + codebook write
__global__ __launch_bounds__(256, 4)
void tail_update(const float* __restrict__ x,
                 const int* __restrict__ indices,
                 const float* __restrict__ ema_cs,
                 const float* __restrict__ ema_w,
                 const double* __restrict__ loss_buckets,
                 int* __restrict__ counts,
                 int* __restrict__ offsets,
                 int* __restrict__ cursor,
                 int* __restrict__ row_sorted,
                 float* __restrict__ cs_ws,
                 float* __restrict__ out_loss,
                 float* __restrict__ out_perp,
                 float* __restrict__ out_ncs,
                 float* __restrict__ out_emb,
                 float* __restrict__ out_ema)
{
    cg::grid_group grid = cg::this_grid();
    __shared__ int    hist[1024];
    __shared__ int    sci[256];
    __shared__ float  scf[256];
    __shared__ double scd[256];
    __shared__ int    rows[2048];

    const int t = threadIdx.x;
    const int b = blockIdx.x;

    // ---- Phase A: histogram (blocks 0-15; counts pre-zeroed by prep_e) ----
    if (b < 16) {
#pragma unroll
        for (int i = 0; i < 4; ++i) hist[i * 256 + t] = 0;
        __syncthreads();
        const int base = b * 4096 + t * 16;
#pragma unroll
        for (int i = 0; i < 4; ++i) {
            int4 v = *(const int4*)(indices + base + i * 4);
            atomicAdd(&hist[v.x], 1); atomicAdd(&hist[v.y], 1);
            atomicAdd(&hist[v.z], 1); atomicAdd(&hist[v.w], 1);
        }
        __syncthreads();
#pragma unroll
        for (int i = 0; i < 4; ++i) {
            int c = hist[i * 256 + t];
            if (c) atomicAdd(&counts[i * 256 + t], c);
        }
    }
    grid.sync();

    // ---- Phase B: block 0: scan + scalars + cursor zero ----
    if (b == 0) {
        int   c4[4];
        float ncs4[4];
        int   s = 0;
        float npart = 0.0f;
#pragma unroll
        for (int j = 0; j < 4; ++j) {
            const int k4 = t * 4 + j;
            c4[j] = counts[k4];
            s += c4[j];
            ncs4[j] = 0.99f * ema_cs[k4] + 0.01f * (float)c4[j];
            out_ncs[k4] = ncs4[j];
            npart += ncs4[j];
        }
        sci[t] = s;
        scf[t] = npart;
        __syncthreads();
        // Hillis-Steele inclusive scan of the 256 group sums
        for (int d = 1; d < 256; d <<= 1) {
            int add = (t >= d) ? sci[t - d] : 0;
            __syncthreads();
            sci[t] += add;
            __syncthreads();
        }
        const int excl_base = sci[t] - s;
        // total n = sum(ncs) via tree reduce on scf
        for (int off = 128; off > 0; off >>= 1) {
            if (t < off) scf[t] += scf[t + off];
            __syncthreads();
        }
        const float n = scf[0];
        __syncthreads();
        int run = excl_base;
        float ppart = 0.0f;
#pragma unroll
        for (int j = 0; j < 4; ++j) {
            const int k4 = t * 4 + j;
            offsets[k4] = run; run += c4[j];
            cursor[k4]  = 0;
            cs_ws[k4] = (ncs4[j] + 1e-5f) / (n + 1024.0f * 1e-5f) * n;
            const float p = (float)c4[j] / 65536.0f;
            ppart += p * logf(p + 1e-10f);
        }
        scf[t] = ppart;
        scd[t] = loss_buckets[t];
        __syncthreads();
        for (int off = 128; off > 0; off >>= 1) {
            if (t < off) { scf[t] += scf[t + off]; scd[t] += scd[t + off]; }
            __syncthreads();
        }
        if (t == 0) {
            out_perp[0] = expf(-scf[0]);
            out_loss[0] = (float)(0.25 * (scd[0] / 16777216.0));
        }
    }
    grid.sync();

    // ---- Phase C: scatter (all 512 blocks, 128 rows each) ----
    if (t < 128) {
        const int row = b * 128 + t;
        const int idx = indices[row];
        const int pos = atomicAdd(&cursor[idx], 1);
        row_sorted[offsets[idx] + pos] = row;
    }
    grid.sync();

    // ---- Phase D: gather + EMA + normalize (block b -> codes 2b, 2b+1) ----
    for (int kk = 2 * b; kk < 2 * b + 2; ++kk) {
        const int off = offsets[kk];
        const int cnt = counts[kk];
        float sum = 0.0f;   // thread owns dim t
        for (int c = 0; c < cnt; c += 2048) {
            const int m = min(cnt - c, 2048);
            for (int i = t; i < m; i += 256) rows[i] = row_sorted[off + c + i];
            __syncthreads();
            int r = 0;
            for (; r + 4 <= m; r += 4) {
                int i0 = rows[r], i1 = rows[r + 1], i2 = rows[r + 2], i3 = rows[r + 3];
                float v0 = x[(size_t)i0 * D_EMB + t];
                float v1 = x[(size_t)i1 * D_EMB + t];
                float v2 = x[(size_t)i2 * D_EMB + t];
                float v3 = x[(size_t)i3 * D_EMB + t];
                sum += (v0 + v1) + (v2 + v3);
            }
            for (; r < m; ++r)
                sum += x[(size_t)rows[r] * D_EMB + t];
            __syncthreads();
        }
        const size_t o = (size_t)kk * D_EMB + t;
        const float nev = 0.99f * ema_w[o] + 0.01f * sum;
        out_ema[o] = nev;
        out_emb[o] = nev / cs_ws[kk];
    }
}

extern "C" void kernel_launch(void* const* d_in, const int* in_sizes, int n_in,
                              void* d_out, int out_size, void* d_ws, size_t ws_size,
                              hipStream_t stream)
{
    const float* x       = (const float*)d_in[0];  // 32*2048*256
    const float* ew      = (const float*)d_in[1];  // 1024*256
    const float* ema_cs  = (const float*)d_in[2];  // 1024
    const float* ema_w   = (const float*)d_in[3];  // 1024*256

    float* out       = (float*)d_out;
    float* out_loss  = out;                         // [1]
    float* out_q     = out + 1;                     // [16777216]
    float* out_perp  = out + 1 + 16777216;          // [1]
    float* out_emb   = out_perp + 1;                // [262144]
    float* out_ncs   = out_emb + 262144;            // [1024]
    float* out_ema   = out_ncs + 1024;              // [262144]

    char* ws = (char*)d_ws;
    int*    counts       = (int*)(ws);               // 4,096 B
    double* loss_buckets = (double*)(ws + 4096);     // 2,048 B
    float*  half_esq     = (float*)(ws + 6144);      // 4,096 B
    float*  cs_ws        = (float*)(ws + 10240);     // 4,096 B
    int*    offsets      = (int*)(ws + 14336);       // 4,096 B
    int*    cursor       = (int*)(ws + 18432);       // 4,096 B
    int*    indices      = (int*)(ws + 22528);       // 262,144 B
    int*    row_sorted   = (int*)(ws + 284672);      // 262,144 B

    // fragment-packed bf16 codebook lives in the out_emb/out_ncs region of the
    // output buffer: pack is consumed only by argmin_mfma; out_emb/out_ncs are
    // written later (tail_update phases B/D run after argmin in stream order),
    // so the overlap is safe.
    short* pack_hi = (short*)(out + 16777220);            // 1024*256 shorts
    short* pack_lo = (short*)(out + 16777220 + 131072);   // 1024*256 shorts

    prep_e<<<K_EMB, 64, 0, stream>>>(ew, half_esq, pack_hi, pack_lo,
                                     counts, loss_buckets);
    argmin_mfma<<<N_ROWS / 32, 256, 0, stream>>>(x, pack_hi, pack_lo, half_esq,
                                                 ew, indices, out_q, loss_buckets);

    void* args[] = {
        (void*)&x, (void*)&indices, (void*)&ema_cs, (void*)&ema_w,
        (void*)&loss_buckets, (void*)&counts, (void*)&offsets, (void*)&cursor,
        (void*)&row_sorted, (void*)&cs_ws, (void*)&out_loss, (void*)&out_perp,
        (void*)&out_ncs, (void*)&out_emb, (void*)&out_ema
    };
    hipLaunchCooperativeKernel((void*)tail_update, dim3(512), dim3(256),
                               args, 0, stream);
}

// Round 8
// 253.837 us; speedup vs baseline: 1.6949x; 1.6949x over previous
//
#include <hip/hip_runtime.h>
#include <math.h>

#define N_ROWS   65536
#define K_EMB    1024
#define D_EMB    256

typedef __attribute__((ext_vector_type(8)))  short short8;
typedef __attribute__((ext_vector_type(4)))  short short4v;
typedef __attribute__((ext_vector_type(16))) float floatx16;

__device__ inline unsigned short f2bf(float f) {
    unsigned u = __float_as_uint(f);
    unsigned r = u + 0x7fffu + ((u >> 16) & 1u);
    return (unsigned short)(r >> 16);
}
__device__ inline float bf2f(unsigned short s) {
    return __uint_as_float(((unsigned)s) << 16);
}

// ---------------- prep: 0.5*||e||^2 + negated bf16 hi/lo codebook ----------------
// Pack layout (proven): off = tile*8192 + kt*512 + lane*8 + j  (shorts)
//   tile=code>>5, kt=dim>>4, half=(dim&15)>>3, lane=(code&31)+32*half, j=dim&7.
// Also zeros counts/loss_buckets (no separate memset dispatch).
__global__ __launch_bounds__(64)
void prep_e(const float* __restrict__ ew, float* __restrict__ half_esq,
            short* __restrict__ pack_hi, short* __restrict__ pack_lo,
            int* __restrict__ counts, double* __restrict__ loss_buckets)
{
    const int k = blockIdx.x;
    const int t = threadIdx.x;  // 64 threads, 4 consecutive dims each

    if (t == 0) {
        counts[k] = 0;
        if (k < 256) loss_buckets[k] = 0.0;
    }

    float4 v = *(const float4*)(ew + (size_t)k * D_EMB + t * 4);
    float s = v.x * v.x + v.y * v.y + v.z * v.z + v.w * v.w;
#pragma unroll
    for (int off = 32; off > 0; off >>= 1) s += __shfl_down(s, off);
    if (t == 0) half_esq[k] = 0.5f * s;

    const int d0   = t * 4;
    const int tile = k >> 5;
    const int kt   = d0 >> 4;
    const int half = (d0 & 15) >> 3;
    const int lane = (k & 31) + 32 * half;
    const int j0   = d0 & 7;          // 0 or 4
    const int off  = tile * 8192 + kt * 512 + lane * 8 + j0;

    float f[4] = {-v.x, -v.y, -v.z, -v.w};
    short4v h, l;
#pragma unroll
    for (int j = 0; j < 4; ++j) {
        unsigned short hh = f2bf(f[j]);
        h[j] = (short)hh;
        l[j] = (short)f2bf(f[j] - bf2f(hh));
    }
    *(short4v*)(pack_hi + off) = h;
    *(short4v*)(pack_lo + off) = l;
}

// ---------------- Phase A (fused): MFMA argmin + quantize + loss ----------------
// 64-ROW B-TILE variant of the proven round-2 loop: each block stages 64 x
// rows (64 KB LDS hi+lo); every A-fragment is reused against TWO B column
// groups (x-rows l31 and l31+32) => 12 MFMA per 4 A-loads per kt (2x the
// arithmetic intensity per fetched A-byte) and HALF the total pack L2
// traffic (1024 blocks x 1 MB). The A-prefetch register structure (8 live
// short8, depth-1) is byte-identical to round-2 — that structure is what
// collapsed in the round-1/round-3 failures and is NOT touched here.
// Occupancy: LDS 66.5 KB -> 2 blocks/CU (~8 waves/CU); per-SIMD latency
// coverage 2 waves x 96 cyc ~= the ~200 cyc L2 latency.
// CLOSED levers (measured): 4-code-tile ILP (r1), depth-2 prefetch (r3),
// 8-wave TLP (r5 spill), epilogue histogram atomic (r4), cooperative tail (r7).
__global__ __launch_bounds__(256, 2)
void argmin_mfma(const float* __restrict__ x,
                 const short* __restrict__ pack_hi,
                 const short* __restrict__ pack_lo,
                 const float* __restrict__ half_esq,
                 const float* __restrict__ ew,
                 int* __restrict__ indices,
                 float* __restrict__ out_q,
                 double* __restrict__ loss_buckets)
{
    __shared__ short xs_hi[64 * 256];
    __shared__ short xs_lo[64 * 256];
    __shared__ float cmv[256];
    __shared__ int   cmi[256];
    __shared__ int   widx[64];

    const int t  = threadIdx.x;
    const int r0 = blockIdx.x * 64;

    // ---- stage 64 x rows: fp32 -> bf16 hi/lo, XOR-swizzled ----
#pragma unroll
    for (int i = 0; i < 8; ++i) {
        int q   = i * 256 + t;   // [0,2048)
        int row = q >> 5;        // [0,64)
        int g8  = q & 31;        // 8-float group within row
        const float* gp = x + (size_t)(r0 + row) * D_EMB + g8 * 8;
        float4 a = *(const float4*)gp;
        float4 b = *(const float4*)(gp + 4);
        float f[8] = {a.x, a.y, a.z, a.w, b.x, b.y, b.z, b.w};
        short8 h8, l8;
#pragma unroll
        for (int j = 0; j < 8; ++j) {
            unsigned short hh = f2bf(f[j]);
            h8[j] = (short)hh;
            l8[j] = (short)f2bf(f[j] - bf2f(hh));
        }
        int off = row * 256 + ((g8 ^ (row & 7)) << 3);
        *(short8*)(xs_hi + off) = h8;
        *(short8*)(xs_lo + off) = l8;
    }
    __syncthreads();

    const int w    = t >> 6;     // wave id -> code quarter
    const int lane = t & 63;
    const int l31  = lane & 31;
    const int half = lane >> 5;
    const int key  = l31 & 7;    // swizzle key ((l31+32)&7 == l31&7, shared)
    const short* bbase_h  = xs_hi + l31 * 256;
    const short* bbase_l  = xs_lo + l31 * 256;
    const short* bbase2_h = xs_hi + (l31 + 32) * 256;
    const short* bbase2_l = xs_lo + (l31 + 32) * 256;

    float mv0 = 3.4e38f, mv1 = 3.4e38f;
    int   mi0 = 0,       mi1 = 0;

    for (int cp = 0; cp < 4; ++cp) {
        const int c0 = w * 256 + cp * 64;
        const int c1 = c0 + 32;
        const int tile0 = c0 >> 5;   // tile1 = tile0+1

        floatx16 acc0, acc1, acc2, acc3;
#pragma unroll
        for (int rq = 0; rq < 4; ++rq) {
            float4 e0 = *(const float4*)(half_esq + c0 + rq * 8 + half * 4);
            float4 e1 = *(const float4*)(half_esq + c1 + rq * 8 + half * 4);
            acc0[rq * 4 + 0] = e0.x; acc0[rq * 4 + 1] = e0.y;
            acc0[rq * 4 + 2] = e0.z; acc0[rq * 4 + 3] = e0.w;
            acc1[rq * 4 + 0] = e1.x; acc1[rq * 4 + 1] = e1.y;
            acc1[rq * 4 + 2] = e1.z; acc1[rq * 4 + 3] = e1.w;
#pragma unroll
            for (int j = 0; j < 4; ++j) {
                acc2[rq * 4 + j] = acc0[rq * 4 + j];
                acc3[rq * 4 + j] = acc1[rq * 4 + j];
            }
        }

        // fragment-packed bases: wave reads CONTIGUOUS 1 KB per load
        const short* p0h = pack_hi + tile0 * 8192 + lane * 8;
        const short* p0l = pack_lo + tile0 * 8192 + lane * 8;
        const short* p1h = p0h + 8192;
        const short* p1l = p0l + 8192;

        // depth-1 register prefetch — IDENTICAL structure to round-2
        short8 a0h = *(const short8*)(p0h);
        short8 a0l = *(const short8*)(p0l);
        short8 a1h = *(const short8*)(p1h);
        short8 a1l = *(const short8*)(p1l);

#pragma unroll 4
        for (int kt = 0; kt < 16; ++kt) {
            short8 n0h, n0l, n1h, n1l;
            if (kt < 15) {
                n0h = *(const short8*)(p0h + (kt + 1) * 512);
                n0l = *(const short8*)(p0l + (kt + 1) * 512);
                n1h = *(const short8*)(p1h + (kt + 1) * 512);
                n1l = *(const short8*)(p1l + (kt + 1) * 512);
            }
            int coff = (((2 * kt + half) ^ key) << 3);
            short8 bh  = *(const short8*)(bbase_h  + coff);
            short8 bl  = *(const short8*)(bbase_l  + coff);
            short8 bh2 = *(const short8*)(bbase2_h + coff);
            short8 bl2 = *(const short8*)(bbase2_l + coff);
            acc0 = __builtin_amdgcn_mfma_f32_32x32x16_bf16(a0h, bh,  acc0, 0, 0, 0);
            acc1 = __builtin_amdgcn_mfma_f32_32x32x16_bf16(a1h, bh,  acc1, 0, 0, 0);
            acc2 = __builtin_amdgcn_mfma_f32_32x32x16_bf16(a0h, bh2, acc2, 0, 0, 0);
            acc3 = __builtin_amdgcn_mfma_f32_32x32x16_bf16(a1h, bh2, acc3, 0, 0, 0);
            acc0 = __builtin_amdgcn_mfma_f32_32x32x16_bf16(a0h, bl,  acc0, 0, 0, 0);
            acc1 = __builtin_amdgcn_mfma_f32_32x32x16_bf16(a1h, bl,  acc1, 0, 0, 0);
            acc2 = __builtin_amdgcn_mfma_f32_32x32x16_bf16(a0h, bl2, acc2, 0, 0, 0);
            acc3 = __builtin_amdgcn_mfma_f32_32x32x16_bf16(a1h, bl2, acc3, 0, 0, 0);
            acc0 = __builtin_amdgcn_mfma_f32_32x32x16_bf16(a0l, bh,  acc0, 0, 0, 0);
            acc1 = __builtin_amdgcn_mfma_f32_32x32x16_bf16(a1l, bh,  acc1, 0, 0, 0);
            acc2 = __builtin_amdgcn_mfma_f32_32x32x16_bf16(a0l, bh2, acc2, 0, 0, 0);
            acc3 = __builtin_amdgcn_mfma_f32_32x32x16_bf16(a1l, bh2, acc3, 0, 0, 0);
            a0h = n0h; a0l = n0l; a1h = n1h; a1l = n1l;
        }

        // fold: C row = code-in-tile = (r&3) + 8*(r>>2) + 4*half
        // acc0/acc1 -> x-row l31; acc2/acc3 -> x-row l31+32
#pragma unroll
        for (int r = 0; r < 16; ++r) {
            int code0 = c0 + (r & 3) + ((r >> 2) << 3) + half * 4;
            int code1 = code0 + 32;
            float v;
            v = acc0[r]; if (v < mv0 || (v == mv0 && code0 < mi0)) { mv0 = v; mi0 = code0; }
            v = acc1[r]; if (v < mv0 || (v == mv0 && code1 < mi0)) { mv0 = v; mi0 = code1; }
            v = acc2[r]; if (v < mv1 || (v == mv1 && code0 < mi1)) { mv1 = v; mi1 = code0; }
            v = acc3[r]; if (v < mv1 || (v == mv1 && code1 < mi1)) { mv1 = v; mi1 = code1; }
        }
    }

    // combine the two 32-lane halves (disjoint code subsets, same x-row)
    {
        float ov = __shfl_xor(mv0, 32);
        int   oi = __shfl_xor(mi0, 32);
        if (ov < mv0 || (ov == mv0 && oi < mi0)) { mv0 = ov; mi0 = oi; }
        ov = __shfl_xor(mv1, 32);
        oi = __shfl_xor(mi1, 32);
        if (ov < mv1 || (ov == mv1 && oi < mi1)) { mv1 = ov; mi1 = oi; }
    }

    // cross-wave (code-quarter) combine via dedicated LDS scratch (xs intact)
    if (half == 0) {
        cmv[w * 64 + l31]      = mv0;
        cmi[w * 64 + l31]      = mi0;
        cmv[w * 64 + 32 + l31] = mv1;
        cmi[w * 64 + 32 + l31] = mi1;
    }
    __syncthreads();
    if (t < 64) {
        float bv = cmv[t];
        int   bi = cmi[t];
#pragma unroll
        for (int ww = 1; ww < 4; ++ww) {
            float v = cmv[ww * 64 + t];
            int   i = cmi[ww * 64 + t];
            if (v < bv || (v == bv && i < bi)) { bv = v; bi = i; }
        }
        indices[r0 + t] = bi;
        widx[t] = bi;
    }
    __syncthreads();

    // ---- fused epilogue: quantize + commitment-loss partial ----
    // xv reconstructed from the staged LDS tile: no second global x read.
    const int g8e  = lane >> 1;            // dim group of this lane's 4 dims
    const int j0e  = (lane & 1) * 4;       // offset within the 8-group
    float lsum = 0.0f;
#pragma unroll
    for (int rr = 0; rr < 16; ++rr) {
        const int row = w * 16 + rr;           // wave handles 16 rows
        const int idx = widx[row];             // wave-uniform
        const int off = row * 256 + (((g8e) ^ (row & 7)) << 3) + j0e;
        short4v h4 = *(const short4v*)(xs_hi + off);
        short4v l4 = *(const short4v*)(xs_lo + off);
        float xr[4];
#pragma unroll
        for (int j = 0; j < 4; ++j)
            xr[j] = bf2f((unsigned short)h4[j]) + bf2f((unsigned short)l4[j]);
        const float4 ev = *(const float4*)(ew + (size_t)idx * D_EMB + lane * 4);
        float4 q;
        q.x = xr[0] + (ev.x - xr[0]);
        q.y = xr[1] + (ev.y - xr[1]);
        q.z = xr[2] + (ev.z - xr[2]);
        q.w = xr[3] + (ev.w - xr[3]);
        *(float4*)(out_q + (size_t)(r0 + row) * D_EMB + lane * 4) = q;
        float dx = ev.x - xr[0], dy = ev.y - xr[1];
        float dz = ev.z - xr[2], dwv = ev.w - xr[3];
        lsum += dx * dx + dy * dy + dz * dz + dwv * dwv;
    }
#pragma unroll
    for (int off = 32; off > 0; off >>= 1) lsum += __shfl_down(lsum, off);
    if (lane == 0) atomicAdd(&loss_buckets[blockIdx.x & 255], (double)lsum);
}

// ---------------- histogram of indices (off argmin's critical path) ----------
__global__ __launch_bounds__(256)
void histogram(const int* __restrict__ indices, int* __restrict__ counts)
{
    __shared__ int h[1024];
    const int t = threadIdx.x;
#pragma unroll
    for (int i = 0; i < 4; ++i) h[i * 256 + t] = 0;
    __syncthreads();
    const int base = blockIdx.x * 4096 + t * 16;
#pragma unroll
    for (int i = 0; i < 4; ++i) {
        int4 v = *(const int4*)(indices + base + i * 4);
        atomicAdd(&h[v.x], 1); atomicAdd(&h[v.y], 1);
        atomicAdd(&h[v.z], 1); atomicAdd(&h[v.w], 1);
    }
    __syncthreads();
#pragma unroll
    for (int i = 0; i < 4; ++i) {
        int c = h[i * 256 + t];
        if (c) atomicAdd(&counts[i * 256 + t], c);
    }
}

// ---------------- C1: scalars + cluster sizes + PREFIX-SUM offsets ----------------
__global__ __launch_bounds__(1024)
void finalize_small(const float* __restrict__ ema_cs,
                    const int* __restrict__ counts,
                    const double* __restrict__ loss_buckets,
                    float* __restrict__ cs_ws,
                    float* __restrict__ out_loss,
                    float* __restrict__ out_perp,
                    float* __restrict__ out_ncs,
                    int* __restrict__ offsets,
                    int* __restrict__ cursor)
{
    __shared__ float  red[1024];
    __shared__ double redd[256];
    __shared__ int    sc[1024];
    const int k = threadIdx.x;
    const int icnt = counts[k];
    const float cnt = (float)icnt;
    const float ncs = 0.99f * ema_cs[k] + 0.01f * cnt;
    out_ncs[k] = ncs;
    red[k] = ncs;
    sc[k]  = icnt;
    __syncthreads();
    for (int off = 512; off > 0; off >>= 1) {
        if (k < off) red[k] += red[k + off];
        __syncthreads();
    }
    const float n = red[0];
    __syncthreads();
    cs_ws[k] = (ncs + 1e-5f) / (n + 1024.0f * 1e-5f) * n;

    // Hillis-Steele inclusive scan of counts -> exclusive offsets
    for (int d = 1; d < 1024; d <<= 1) {
        int add = (k >= d) ? sc[k - d] : 0;
        __syncthreads();
        sc[k] += add;
        __syncthreads();
    }
    offsets[k] = sc[k] - icnt;
    cursor[k]  = 0;

    const float p = cnt / 65536.0f;
    red[k] = p * logf(p + 1e-10f);
    if (k < 256) redd[k] = loss_buckets[k];
    __syncthreads();
    for (int off = 512; off > 0; off >>= 1) {
        if (k < off) red[k] += red[k + off];
        __syncthreads();
    }
    if (k == 0) out_perp[0] = expf(-red[0]);
    for (int off = 128; off > 0; off >>= 1) {
        if (k < off) redd[k] += redd[k + off];
        __syncthreads();
    }
    if (k == 0) out_loss[0] = (float)(0.25 * (redd[0] / 16777216.0));
}

// ---------------- B1: counting-sort scatter of row ids ----------------
__global__ __launch_bounds__(256)
void scatter_rows(const int* __restrict__ indices,
                  const int* __restrict__ offsets,
                  int* __restrict__ cursor,
                  int* __restrict__ row_sorted)
{
    const int row = blockIdx.x * 256 + threadIdx.x;
    const int idx = indices[row];
    const int pos = atomicAdd(&cursor[idx], 1);
    row_sorted[offsets[idx] + pos] = row;
}

// ---------------- B2 (fused with codebook update): gather + EMA + normalize ----
__global__ __launch_bounds__(256)
void gather_update(const float* __restrict__ x,
                   const int* __restrict__ row_sorted,
                   const int* __restrict__ offsets,
                   const int* __restrict__ counts,
                   const float* __restrict__ ema_w,
                   const float* __restrict__ cs_ws,
                   float* __restrict__ out_emb,
                   float* __restrict__ out_ema)
{
    __shared__ int rows[2048];
    const int k   = blockIdx.x;
    const int t   = threadIdx.x;
    const int off = offsets[k];
    const int cnt = counts[k];
    float sum = 0.0f;   // thread owns dim t

    for (int c = 0; c < cnt; c += 2048) {
        const int m = min(cnt - c, 2048);
        for (int i = t; i < m; i += 256) rows[i] = row_sorted[off + c + i];
        __syncthreads();
        int r = 0;
        for (; r + 4 <= m; r += 4) {
            int i0 = rows[r], i1 = rows[r + 1], i2 = rows[r + 2], i3 = rows[r + 3];
            float v0 = x[(size_t)i0 * D_EMB + t];
            float v1 = x[(size_t)i1 * D_EMB + t];
            float v2 = x[(size_t)i2 * D_EMB + t];
            float v3 = x[(size_t)i3 * D_EMB + t];
            sum += (v0 + v1) + (v2 + v3);
        }
        for (; r < m; ++r)
            sum += x[(size_t)rows[r] * D_EMB + t];
        __syncthreads();
    }

    const size_t o = (size_t)k * D_EMB + t;
    const float nev = 0.99f * ema_w[o] + 0.01f * sum;
    out_ema[o] = nev;
    out_emb[o] = nev / cs_ws[k];
}

extern "C" void kernel_launch(void* const* d_in, const int* in_sizes, int n_in,
                              void* d_out, int out_size, void* d_ws, size_t ws_size,
                              hipStream_t stream)
{
    const float* x       = (const float*)d_in[0];  // 32*2048*256
    const float* ew      = (const float*)d_in[1];  // 1024*256
    const float* ema_cs  = (const float*)d_in[2];  // 1024
    const float* ema_w   = (const float*)d_in[3];  // 1024*256

    float* out       = (float*)d_out;
    float* out_loss  = out;                         // [1]
    float* out_q     = out + 1;                     // [16777216]
    float* out_perp  = out + 1 + 16777216;          // [1]
    float* out_emb   = out_perp + 1;                // [262144]
    float* out_ncs   = out_emb + 262144;            // [1024]
    float* out_ema   = out_ncs + 1024;              // [262144]

    char* ws = (char*)d_ws;
    int*    counts       = (int*)(ws);               // 4,096 B
    double* loss_buckets = (double*)(ws + 4096);     // 2,048 B
    float*  half_esq     = (float*)(ws + 6144);      // 4,096 B
    float*  cs_ws        = (float*)(ws + 10240);     // 4,096 B
    int*    offsets      = (int*)(ws + 14336);       // 4,096 B
    int*    cursor       = (int*)(ws + 18432);       // 4,096 B
    int*    indices      = (int*)(ws + 22528);       // 262,144 B
    int*    row_sorted   = (int*)(ws + 284672);      // 262,144 B

    // fragment-packed bf16 codebook lives in the out_emb/out_ncs region of the
    // output buffer: pack is consumed only by argmin_mfma; out_emb/out_ncs are
    // written later (gather_update / finalize_small run after argmin in stream
    // order), so the overlap is safe.
    short* pack_hi = (short*)(out + 16777220);            // 1024*256 shorts
    short* pack_lo = (short*)(out + 16777220 + 131072);   // 1024*256 shorts

    prep_e<<<K_EMB, 64, 0, stream>>>(ew, half_esq, pack_hi, pack_lo,
                                     counts, loss_buckets);
    argmin_mfma<<<N_ROWS / 64, 256, 0, stream>>>(x, pack_hi, pack_lo, half_esq,
                                                 ew, indices, out_q, loss_buckets);
    histogram<<<16, 256, 0, stream>>>(indices, counts);
    finalize_small<<<1, 1024, 0, stream>>>(ema_cs, counts, loss_buckets, cs_ws,
                                           out_loss, out_perp, out_ncs,
                                           offsets, cursor);
    scatter_rows<<<N_ROWS / 256, 256, 0, stream>>>(indices, offsets, cursor,
                                                   row_sorted);
    gather_update<<<K_EMB, 256, 0, stream>>>(x, row_sorted, offsets, counts,
                                             ema_w, cs_ws, out_emb, out_ema);
}

// Round 9
// 249.315 us; speedup vs baseline: 1.7256x; 1.0181x over previous
//
#include <hip/hip_runtime.h>
#include <math.h>

#define N_ROWS   65536
#define K_EMB    1024
#define D_EMB    256

typedef __attribute__((ext_vector_type(8)))  short short8;
typedef __attribute__((ext_vector_type(4)))  short short4v;
typedef __attribute__((ext_vector_type(16))) float floatx16;

__device__ inline unsigned short f2bf(float f) {
    unsigned u = __float_as_uint(f);
    unsigned r = u + 0x7fffu + ((u >> 16) & 1u);
    return (unsigned short)(r >> 16);
}
__device__ inline float bf2f(unsigned short s) {
    return __uint_as_float(((unsigned)s) << 16);
}

// ---------------- prep: 0.5*||e||^2 + negated bf16 hi/lo codebook ----------------
// Pack layout (proven): off = tile*8192 + kt*512 + lane*8 + j  (shorts)
//   tile=code>>5, kt=dim>>4, half=(dim&15)>>3, lane=(code&31)+32*half, j=dim&7.
// Also zeros counts/loss_buckets (no separate memset dispatch).
__global__ __launch_bounds__(64)
void prep_e(const float* __restrict__ ew, float* __restrict__ half_esq,
            short* __restrict__ pack_hi, short* __restrict__ pack_lo,
            int* __restrict__ counts, double* __restrict__ loss_buckets)
{
    const int k = blockIdx.x;
    const int t = threadIdx.x;  // 64 threads, 4 consecutive dims each

    if (t == 0) {
        counts[k] = 0;
        if (k < 256) loss_buckets[k] = 0.0;
    }

    float4 v = *(const float4*)(ew + (size_t)k * D_EMB + t * 4);
    float s = v.x * v.x + v.y * v.y + v.z * v.z + v.w * v.w;
#pragma unroll
    for (int off = 32; off > 0; off >>= 1) s += __shfl_down(s, off);
    if (t == 0) half_esq[k] = 0.5f * s;

    const int d0   = t * 4;
    const int tile = k >> 5;
    const int kt   = d0 >> 4;
    const int half = (d0 & 15) >> 3;
    const int lane = (k & 31) + 32 * half;
    const int j0   = d0 & 7;          // 0 or 4
    const int off  = tile * 8192 + kt * 512 + lane * 8 + j0;

    float f[4] = {-v.x, -v.y, -v.z, -v.w};
    short4v h, l;
#pragma unroll
    for (int j = 0; j < 4; ++j) {
        unsigned short hh = f2bf(f[j]);
        h[j] = (short)hh;
        l[j] = (short)f2bf(f[j] - bf2f(hh));
    }
    *(short4v*)(pack_hi + off) = h;
    *(short4v*)(pack_lo + off) = l;
}

// ---------------- Phase A (fused): MFMA argmin + quantize + loss ----------------
// Round-8 64-row B-tile loop (127 us, MfmaUtil 36%) at DOUBLE the wave pool:
// 512 threads = 8 waves x 128 codes each (2 cp passes). Per-wave code,
// register footprint (88 VGPR), and A-prefetch structure are byte-identical
// to round 8; LDS (68 KB -> 2 blocks/CU) now carries 16 waves/CU instead
// of 8. Register tier check: 88 <= 128-reg cap of __launch_bounds__(512,4),
// so no spill (round 5's failure was cap 64 < ~88 — the 8-wave/SIMD tier).
// CLOSED levers (measured): 4-code-tile ILP (r1), depth-2 prefetch (r3),
// 8-wave/SIMD TLP (r5 spill), epilogue histogram atomic (r4), coop tail (r7).
__global__ __launch_bounds__(512, 4)
void argmin_mfma(const float* __restrict__ x,
                 const short* __restrict__ pack_hi,
                 const short* __restrict__ pack_lo,
                 const float* __restrict__ half_esq,
                 const float* __restrict__ ew,
                 int* __restrict__ indices,
                 float* __restrict__ out_q,
                 double* __restrict__ loss_buckets)
{
    __shared__ short xs_hi[64 * 256];
    __shared__ short xs_lo[64 * 256];
    __shared__ float cmv[512];
    __shared__ int   cmi[512];
    __shared__ int   widx[64];

    const int t  = threadIdx.x;
    const int r0 = blockIdx.x * 64;

    // ---- stage 64 x rows: fp32 -> bf16 hi/lo, XOR-swizzled ----
#pragma unroll
    for (int i = 0; i < 4; ++i) {
        int q   = i * 512 + t;   // [0,2048)
        int row = q >> 5;        // [0,64)
        int g8  = q & 31;        // 8-float group within row
        const float* gp = x + (size_t)(r0 + row) * D_EMB + g8 * 8;
        float4 a = *(const float4*)gp;
        float4 b = *(const float4*)(gp + 4);
        float f[8] = {a.x, a.y, a.z, a.w, b.x, b.y, b.z, b.w};
        short8 h8, l8;
#pragma unroll
        for (int j = 0; j < 8; ++j) {
            unsigned short hh = f2bf(f[j]);
            h8[j] = (short)hh;
            l8[j] = (short)f2bf(f[j] - bf2f(hh));
        }
        int off = row * 256 + ((g8 ^ (row & 7)) << 3);
        *(short8*)(xs_hi + off) = h8;
        *(short8*)(xs_lo + off) = l8;
    }
    __syncthreads();

    const int w    = t >> 6;     // wave id [0,8) -> 128-code slice
    const int lane = t & 63;
    const int l31  = lane & 31;
    const int half = lane >> 5;
    const int key  = l31 & 7;    // swizzle key ((l31+32)&7 == l31&7, shared)
    const short* bbase_h  = xs_hi + l31 * 256;
    const short* bbase_l  = xs_lo + l31 * 256;
    const short* bbase2_h = xs_hi + (l31 + 32) * 256;
    const short* bbase2_l = xs_lo + (l31 + 32) * 256;

    float mv0 = 3.4e38f, mv1 = 3.4e38f;
    int   mi0 = 0,       mi1 = 0;

    for (int cp = 0; cp < 2; ++cp) {
        const int c0 = w * 128 + cp * 64;
        const int c1 = c0 + 32;
        const int tile0 = c0 >> 5;   // tile1 = tile0+1

        floatx16 acc0, acc1, acc2, acc3;
#pragma unroll
        for (int rq = 0; rq < 4; ++rq) {
            float4 e0 = *(const float4*)(half_esq + c0 + rq * 8 + half * 4);
            float4 e1 = *(const float4*)(half_esq + c1 + rq * 8 + half * 4);
            acc0[rq * 4 + 0] = e0.x; acc0[rq * 4 + 1] = e0.y;
            acc0[rq * 4 + 2] = e0.z; acc0[rq * 4 + 3] = e0.w;
            acc1[rq * 4 + 0] = e1.x; acc1[rq * 4 + 1] = e1.y;
            acc1[rq * 4 + 2] = e1.z; acc1[rq * 4 + 3] = e1.w;
#pragma unroll
            for (int j = 0; j < 4; ++j) {
                acc2[rq * 4 + j] = acc0[rq * 4 + j];
                acc3[rq * 4 + j] = acc1[rq * 4 + j];
            }
        }

        // fragment-packed bases: wave reads CONTIGUOUS 1 KB per load
        const short* p0h = pack_hi + tile0 * 8192 + lane * 8;
        const short* p0l = pack_lo + tile0 * 8192 + lane * 8;
        const short* p1h = p0h + 8192;
        const short* p1l = p0l + 8192;

        // depth-1 register prefetch — IDENTICAL structure to round-2/8
        short8 a0h = *(const short8*)(p0h);
        short8 a0l = *(const short8*)(p0l);
        short8 a1h = *(const short8*)(p1h);
        short8 a1l = *(const short8*)(p1l);

#pragma unroll 4
        for (int kt = 0; kt < 16; ++kt) {
            short8 n0h, n0l, n1h, n1l;
            if (kt < 15) {
                n0h = *(const short8*)(p0h + (kt + 1) * 512);
                n0l = *(const short8*)(p0l + (kt + 1) * 512);
                n1h = *(const short8*)(p1h + (kt + 1) * 512);
                n1l = *(const short8*)(p1l + (kt + 1) * 512);
            }
            int coff = (((2 * kt + half) ^ key) << 3);
            short8 bh  = *(const short8*)(bbase_h  + coff);
            short8 bl  = *(const short8*)(bbase_l  + coff);
            short8 bh2 = *(const short8*)(bbase2_h + coff);
            short8 bl2 = *(const short8*)(bbase2_l + coff);
            acc0 = __builtin_amdgcn_mfma_f32_32x32x16_bf16(a0h, bh,  acc0, 0, 0, 0);
            acc1 = __builtin_amdgcn_mfma_f32_32x32x16_bf16(a1h, bh,  acc1, 0, 0, 0);
            acc2 = __builtin_amdgcn_mfma_f32_32x32x16_bf16(a0h, bh2, acc2, 0, 0, 0);
            acc3 = __builtin_amdgcn_mfma_f32_32x32x16_bf16(a1h, bh2, acc3, 0, 0, 0);
            acc0 = __builtin_amdgcn_mfma_f32_32x32x16_bf16(a0h, bl,  acc0, 0, 0, 0);
            acc1 = __builtin_amdgcn_mfma_f32_32x32x16_bf16(a1h, bl,  acc1, 0, 0, 0);
            acc2 = __builtin_amdgcn_mfma_f32_32x32x16_bf16(a0h, bl2, acc2, 0, 0, 0);
            acc3 = __builtin_amdgcn_mfma_f32_32x32x16_bf16(a1h, bl2, acc3, 0, 0, 0);
            acc0 = __builtin_amdgcn_mfma_f32_32x32x16_bf16(a0l, bh,  acc0, 0, 0, 0);
            acc1 = __builtin_amdgcn_mfma_f32_32x32x16_bf16(a1l, bh,  acc1, 0, 0, 0);
            acc2 = __builtin_amdgcn_mfma_f32_32x32x16_bf16(a0l, bh2, acc2, 0, 0, 0);
            acc3 = __builtin_amdgcn_mfma_f32_32x32x16_bf16(a1l, bh2, acc3, 0, 0, 0);
            a0h = n0h; a0l = n0l; a1h = n1h; a1l = n1l;
        }

        // fold: C row = code-in-tile = (r&3) + 8*(r>>2) + 4*half
        // acc0/acc1 -> x-row l31; acc2/acc3 -> x-row l31+32
#pragma unroll
        for (int r = 0; r < 16; ++r) {
            int code0 = c0 + (r & 3) + ((r >> 2) << 3) + half * 4;
            int code1 = code0 + 32;
            float v;
            v = acc0[r]; if (v < mv0 || (v == mv0 && code0 < mi0)) { mv0 = v; mi0 = code0; }
            v = acc1[r]; if (v < mv0 || (v == mv0 && code1 < mi0)) { mv0 = v; mi0 = code1; }
            v = acc2[r]; if (v < mv1 || (v == mv1 && code0 < mi1)) { mv1 = v; mi1 = code0; }
            v = acc3[r]; if (v < mv1 || (v == mv1 && code1 < mi1)) { mv1 = v; mi1 = code1; }
        }
    }

    // combine the two 32-lane halves (disjoint code subsets, same x-row)
    {
        float ov = __shfl_xor(mv0, 32);
        int   oi = __shfl_xor(mi0, 32);
        if (ov < mv0 || (ov == mv0 && oi < mi0)) { mv0 = ov; mi0 = oi; }
        ov = __shfl_xor(mv1, 32);
        oi = __shfl_xor(mi1, 32);
        if (ov < mv1 || (ov == mv1 && oi < mi1)) { mv1 = ov; mi1 = oi; }
    }

    // cross-wave (code-slice) combine via dedicated LDS scratch (xs intact)
    if (half == 0) {
        cmv[w * 64 + l31]      = mv0;
        cmi[w * 64 + l31]      = mi0;
        cmv[w * 64 + 32 + l31] = mv1;
        cmi[w * 64 + 32 + l31] = mi1;
    }
    __syncthreads();
    if (t < 64) {
        float bv = cmv[t];
        int   bi = cmi[t];
#pragma unroll
        for (int ww = 1; ww < 8; ++ww) {
            float v = cmv[ww * 64 + t];
            int   i = cmi[ww * 64 + t];
            if (v < bv || (v == bv && i < bi)) { bv = v; bi = i; }
        }
        indices[r0 + t] = bi;
        widx[t] = bi;
    }
    __syncthreads();

    // ---- fused epilogue: quantize + commitment-loss partial ----
    // xv reconstructed from the staged LDS tile: no second global x read.
    const int g8e  = lane >> 1;            // dim group of this lane's 4 dims
    const int j0e  = (lane & 1) * 4;       // offset within the 8-group
    float lsum = 0.0f;
#pragma unroll
    for (int rr = 0; rr < 8; ++rr) {
        const int row = w * 8 + rr;            // wave handles 8 rows
        const int idx = widx[row];             // wave-uniform
        const int off = row * 256 + (((g8e) ^ (row & 7)) << 3) + j0e;
        short4v h4 = *(const short4v*)(xs_hi + off);
        short4v l4 = *(const short4v*)(xs_lo + off);
        float xr[4];
#pragma unroll
        for (int j = 0; j < 4; ++j)
            xr[j] = bf2f((unsigned short)h4[j]) + bf2f((unsigned short)l4[j]);
        const float4 ev = *(const float4*)(ew + (size_t)idx * D_EMB + lane * 4);
        float4 q;
        q.x = xr[0] + (ev.x - xr[0]);
        q.y = xr[1] + (ev.y - xr[1]);
        q.z = xr[2] + (ev.z - xr[2]);
        q.w = xr[3] + (ev.w - xr[3]);
        *(float4*)(out_q + (size_t)(r0 + row) * D_EMB + lane * 4) = q;
        float dx = ev.x - xr[0], dy = ev.y - xr[1];
        float dz = ev.z - xr[2], dwv = ev.w - xr[3];
        lsum += dx * dx + dy * dy + dz * dz + dwv * dwv;
    }
#pragma unroll
    for (int off = 32; off > 0; off >>= 1) lsum += __shfl_down(lsum, off);
    if (lane == 0) atomicAdd(&loss_buckets[blockIdx.x & 255], (double)lsum);
}

// ---------------- histogram of indices (off argmin's critical path) ----------
__global__ __launch_bounds__(256)
void histogram(const int* __restrict__ indices, int* __restrict__ counts)
{
    __shared__ int h[1024];
    const int t = threadIdx.x;
#pragma unroll
    for (int i = 0; i < 4; ++i) h[i * 256 + t] = 0;
    __syncthreads();
    const int base = blockIdx.x * 4096 + t * 16;
#pragma unroll
    for (int i = 0; i < 4; ++i) {
        int4 v = *(const int4*)(indices + base + i * 4);
        atomicAdd(&h[v.x], 1); atomicAdd(&h[v.y], 1);
        atomicAdd(&h[v.z], 1); atomicAdd(&h[v.w], 1);
    }
    __syncthreads();
#pragma unroll
    for (int i = 0; i < 4; ++i) {
        int c = h[i * 256 + t];
        if (c) atomicAdd(&counts[i * 256 + t], c);
    }
}

// ---------------- C1: scalars + cluster sizes + PREFIX-SUM offsets ----------------
__global__ __launch_bounds__(1024)
void finalize_small(const float* __restrict__ ema_cs,
                    const int* __restrict__ counts,
                    const double* __restrict__ loss_buckets,
                    float* __restrict__ cs_ws,
                    float* __restrict__ out_loss,
                    float* __restrict__ out_perp,
                    float* __restrict__ out_ncs,
                    int* __restrict__ offsets,
                    int* __restrict__ cursor)
{
    __shared__ float  red[1024];
    __shared__ double redd[256];
    __shared__ int    sc[1024];
    const int k = threadIdx.x;
    const int icnt = counts[k];
    const float cnt = (float)icnt;
    const float ncs = 0.99f * ema_cs[k] + 0.01f * cnt;
    out_ncs[k] = ncs;
    red[k] = ncs;
    sc[k]  = icnt;
    __syncthreads();
    for (int off = 512; off > 0; off >>= 1) {
        if (k < off) red[k] += red[k + off];
        __syncthreads();
    }
    const float n = red[0];
    __syncthreads();
    cs_ws[k] = (ncs + 1e-5f) / (n + 1024.0f * 1e-5f) * n;

    // Hillis-Steele inclusive scan of counts -> exclusive offsets
    for (int d = 1; d < 1024; d <<= 1) {
        int add = (k >= d) ? sc[k - d] : 0;
        __syncthreads();
        sc[k] += add;
        __syncthreads();
    }
    offsets[k] = sc[k] - icnt;
    cursor[k]  = 0;

    const float p = cnt / 65536.0f;
    red[k] = p * logf(p + 1e-10f);
    if (k < 256) redd[k] = loss_buckets[k];
    __syncthreads();
    for (int off = 512; off > 0; off >>= 1) {
        if (k < off) red[k] += red[k + off];
        __syncthreads();
    }
    if (k == 0) out_perp[0] = expf(-red[0]);
    for (int off = 128; off > 0; off >>= 1) {
        if (k < off) redd[k] += redd[k + off];
        __syncthreads();
    }
    if (k == 0) out_loss[0] = (float)(0.25 * (redd[0] / 16777216.0));
}

// ---------------- B1: counting-sort scatter of row ids ----------------
__global__ __launch_bounds__(256)
void scatter_rows(const int* __restrict__ indices,
                  const int* __restrict__ offsets,
                  int* __restrict__ cursor,
                  int* __restrict__ row_sorted)
{
    const int row = blockIdx.x * 256 + threadIdx.x;
    const int idx = indices[row];
    const int pos = atomicAdd(&cursor[idx], 1);
    row_sorted[offsets[idx] + pos] = row;
}

// ---------------- B2 (fused with codebook update): gather + EMA + normalize ----
__global__ __launch_bounds__(256)
void gather_update(const float* __restrict__ x,
                   const int* __restrict__ row_sorted,
                   const int* __restrict__ offsets,
                   const int* __restrict__ counts,
                   const float* __restrict__ ema_w,
                   const float* __restrict__ cs_ws,
                   float* __restrict__ out_emb,
                   float* __restrict__ out_ema)
{
    __shared__ int rows[2048];
    const int k   = blockIdx.x;
    const int t   = threadIdx.x;
    const int off = offsets[k];
    const int cnt = counts[k];
    float sum = 0.0f;   // thread owns dim t

    for (int c = 0; c < cnt; c += 2048) {
        const int m = min(cnt - c, 2048);
        for (int i = t; i < m; i += 256) rows[i] = row_sorted[off + c + i];
        __syncthreads();
        int r = 0;
        for (; r + 4 <= m; r += 4) {
            int i0 = rows[r], i1 = rows[r + 1], i2 = rows[r + 2], i3 = rows[r + 3];
            float v0 = x[(size_t)i0 * D_EMB + t];
            float v1 = x[(size_t)i1 * D_EMB + t];
            float v2 = x[(size_t)i2 * D_EMB + t];
            float v3 = x[(size_t)i3 * D_EMB + t];
            sum += (v0 + v1) + (v2 + v3);
        }
        for (; r < m; ++r)
            sum += x[(size_t)rows[r] * D_EMB + t];
        __syncthreads();
    }

    const size_t o = (size_t)k * D_EMB + t;
    const float nev = 0.99f * ema_w[o] + 0.01f * sum;
    out_ema[o] = nev;
    out_emb[o] = nev / cs_ws[k];
}

extern "C" void kernel_launch(void* const* d_in, const int* in_sizes, int n_in,
                              void* d_out, int out_size, void* d_ws, size_t ws_size,
                              hipStream_t stream)
{
    const float* x       = (const float*)d_in[0];  // 32*2048*256
    const float* ew      = (const float*)d_in[1];  // 1024*256
    const float* ema_cs  = (const float*)d_in[2];  // 1024
    const float* ema_w   = (const float*)d_in[3];  // 1024*256

    float* out       = (float*)d_out;
    float* out_loss  = out;                         // [1]
    float* out_q     = out + 1;                     // [16777216]
    float* out_perp  = out + 1 + 16777216;          // [1]
    float* out_emb   = out_perp + 1;                // [262144]
    float* out_ncs   = out_emb + 262144;            // [1024]
    float* out_ema   = out_ncs + 1024;              // [262144]

    char* ws = (char*)d_ws;
    int*    counts       = (int*)(ws);               // 4,096 B
    double* loss_buckets = (double*)(ws + 4096);     // 2,048 B
    float*  half_esq     = (float*)(ws + 6144);      // 4,096 B
    float*  cs_ws        = (float*)(ws + 10240);     // 4,096 B
    int*    offsets      = (int*)(ws + 14336);       // 4,096 B
    int*    cursor       = (int*)(ws + 18432);       // 4,096 B
    int*    indices      = (int*)(ws + 22528);       // 262,144 B
    int*    row_sorted   = (int*)(ws + 284672);      // 262,144 B

    // fragment-packed bf16 codebook lives in the out_emb/out_ncs region of the
    // output buffer: pack is consumed only by argmin_mfma; out_emb/out_ncs are
    // written later (gather_update / finalize_small run after argmin in stream
    // order), so the overlap is safe.
    short* pack_hi = (short*)(out + 16777220);            // 1024*256 shorts
    short* pack_lo = (short*)(out + 16777220 + 131072);   // 1024*256 shorts

    prep_e<<<K_EMB, 64, 0, stream>>>(ew, half_esq, pack_hi, pack_lo,
                                     counts, loss_buckets);
    argmin_mfma<<<N_ROWS / 64, 512, 0, stream>>>(x, pack_hi, pack_lo, half_esq,
                                                 ew, indices, out_q, loss_buckets);
    histogram<<<16, 256, 0, stream>>>(indices, counts);
    finalize_small<<<1, 1024, 0, stream>>>(ema_cs, counts, loss_buckets, cs_ws,
                                           out_loss, out_perp, out_ncs,
                                           offsets, cursor);
    scatter_rows<<<N_ROWS / 256, 256, 0, stream>>>(indices, offsets, cursor,
                                                   row_sorted);
    gather_update<<<K_EMB, 256, 0, stream>>>(x, row_sorted, offsets, counts,
                                             ema_w, cs_ws, out_emb, out_ema);
}